// Round 3
// baseline (293.765 us; speedup 1.0000x reference)
//
#include <hip/hip_runtime.h>
#include <math.h>

// Round 11: projection GEMM rebuilt (256x256 tile, BK=32, 8 waves, 3-buffer
// LDS pipeline with counted vmcnt, setprio, XCD-grouped block decode).
//  - Round-10 counters: gemm_qkv 66us, FETCH 150MB (3.5x ideal: A-panels
//    re-fetched by 4 XCDs), MfmaUtil 22% (= dense-peak floor: 15us busy).
//  - 256^2 tile halves LDS-staged bytes; lbid decode puts all 4 n-blocks of
//    an A-panel on ONE XCD (A HBM fetch 144MB -> 36MB).
//  - Depth-2 prefetch, s_waitcnt vmcnt(8/4/0) counted (never drain mid-loop),
//    raw s_barrier, setprio(1) around MFMA cluster.
//  - rope_qk: 31-iter f64 power loop -> 5 predicated f64 multiplies; f64 div
//    -> multiply by 1/2pi.
// attn_fused, cvts, gemm_out unchanged from round 10.
#define B_ 4
#define NQ 512
#define NK 2048
#define C_ 1024
#define H_ 16
#define D_ 64
#define KK 1024

typedef __attribute__((ext_vector_type(8))) _Float16 half8;
typedef __attribute__((ext_vector_type(4))) _Float16 half4;
typedef __attribute__((ext_vector_type(4))) float float4v;

// async global->LDS, 16B per lane (wave-uniform LDS base + lane*16 by HW)
__device__ __forceinline__ void g2l16(const _Float16* g, _Float16* l)
{
    __builtin_amdgcn_global_load_lds(
        (const __attribute__((address_space(1))) unsigned int*)g,
        (__attribute__((address_space(3))) unsigned int*)l, 16, 0, 0);
}

// ---------------------------------------------------------------------------
// All four W [1024][1024] fp32 -> fp16 slots.  blk = w*1024 + row.
// ---------------------------------------------------------------------------
__global__ __launch_bounds__(256) void cvt_w4(const float* __restrict__ W0,
                                              const float* __restrict__ W1,
                                              const float* __restrict__ W2,
                                              const float* __restrict__ W3,
                                              _Float16* __restrict__ W16)
{
    const int w = blockIdx.x >> 10, row = blockIdx.x & 1023;
    const float* src = (w == 0) ? W0 : (w == 1) ? W1 : (w == 2) ? W2 : W3;
    const int col = threadIdx.x * 4;
    float4 f = *(const float4*)(src + (size_t)row * 1024 + col);
    half4 h;
    h[0] = (_Float16)f.x; h[1] = (_Float16)f.y;
    h[2] = (_Float16)f.z; h[3] = (_Float16)f.w;
    *(half4*)(W16 + ((size_t)w << 20) + (size_t)row * 1024 + col) = h;
}

// query/key/value fp32 -> fp16, one row per block (2048 + 8192 + 8192 rows).
__global__ __launch_bounds__(256) void cvt_qkv(const float* __restrict__ q,
                                               const float* __restrict__ k,
                                               const float* __restrict__ v,
                                               _Float16* __restrict__ xq,
                                               _Float16* __restrict__ xk,
                                               _Float16* __restrict__ xv)
{
    const int blk = blockIdx.x;
    const float* src; _Float16* dst; int row;
    if (blk < 2048)       { src = q; dst = xq; row = blk; }
    else if (blk < 10240) { src = k; dst = xk; row = blk - 2048; }
    else                  { src = v; dst = xv; row = blk - 10240; }
    const int col = threadIdx.x * 4;
    float4 f = *(const float4*)(src + (size_t)row * 1024 + col);
    half4 h;
    h[0] = (_Float16)f.x; h[1] = (_Float16)f.y;
    h[2] = (_Float16)f.z; h[3] = (_Float16)f.w;
    *(half4*)(dst + (size_t)row * 1024 + col) = h;
}

// ---------------------------------------------------------------------------
// 256x256-tile projection GEMM, BK=32, 8 waves (2M x 4N), per-wave 128x64.
// 3-buffer LDS (96KB), depth-2 prefetch with counted vmcnt.
// Per wave per tile: 4 global_load_lds (2 A-halves + 2 B-halves, 1KB each),
// 12 ds_read_b128, 32 MFMA.  XOR-chunk swizzle (pre-swizzled global source,
// linear LDS, swizzled read) keeps LDS bank groups evenly loaded.
// Grid 288 linear; decode groups all 4 n-blocks of an m-panel on one XCD.
// ---------------------------------------------------------------------------
__device__ __forceinline__ void stage_tile(const _Float16* gA, const _Float16* gB,
                                           _Float16 (*sA)[8192], _Float16 (*sB)[8192],
                                           int wv, int t, int bf)
{
    const size_t ko = (size_t)t * 32;
    #pragma unroll
    for (int u = 0; u < 2; ++u) {
        g2l16(gA + (size_t)u * 16 * KK + ko, &sA[bf][(wv * 32 + u * 16) * 32]);
        g2l16(gB + (size_t)u * 16 * KK + ko, &sB[bf][(wv * 32 + u * 16) * 32]);
    }
}

__global__ __launch_bounds__(512) void gemm_qkv256(const _Float16* __restrict__ xq,
                                                   const _Float16* __restrict__ xk,
                                                   const _Float16* __restrict__ xv,
                                                   const _Float16* __restrict__ W16,
                                                   _Float16* __restrict__ qhp,
                                                   _Float16* __restrict__ khp,
                                                   _Float16* __restrict__ vtp)
{
    __shared__ _Float16 sA[3][8192];   // 3 x 256x32 fp16 = 48KB
    __shared__ _Float16 sB[3][8192];   // 48KB

    // lbid decode: xcd = lbid&7; each XCD gets whole m-panels (all 4 n-blocks).
    const int lbid = blockIdx.x;            // 0..287
    const int xcd = lbid & 7, seq = lbid >> 3;
    const int y = xcd + 8 * (seq >> 2);     // m-panel id 0..71
    const int n0 = (seq & 3) * 256;

    const _Float16* A; const _Float16* Bw; _Float16* Yh;
    int mode, nsh, m0;
    if (y < 32)      { A = xk; Bw = W16 + (1u << 20); Yh = khp; mode = 0; nsh = 11; m0 = y * 256; }
    else if (y < 64) { A = xv; Bw = W16 + (2u << 20); Yh = vtp; mode = 2; nsh = 11; m0 = (y - 32) * 256; }
    else             { A = xq; Bw = W16;              Yh = qhp; mode = 0; nsh = 9;  m0 = (y - 64) * 256; }

    const int tid = threadIdx.x;
    const int lane = tid & 63, wv = tid >> 6;        // 8 waves
    const int wm = (wv >> 2) * 128, wn = (wv & 3) * 64;
    const int fm = lane & 15, quad = lane >> 4;

    // staging lane geometry: lane covers row (l>>2), chunk (l&3); global
    // source chunk pre-swizzled by row&3 so swizzled read returns identity.
    const int r0 = lane >> 2;
    const int sch = (lane & 3) ^ (r0 & 3);
    const _Float16* gA = A  + (size_t)(m0 + wv * 32 + r0) * KK + sch * 8;
    const _Float16* gB = Bw + (size_t)(n0 + wv * 32 + r0) * KK + sch * 8;

    float4v acc[8][4];
    #pragma unroll
    for (int i = 0; i < 8; ++i)
        #pragma unroll
        for (int j = 0; j < 4; ++j)
            #pragma unroll
            for (int e = 0; e < 4; ++e) acc[i][j][e] = 0.0f;

    // prologue: stage tiles 0 and 1 (8 vm ops in flight per wave)
    stage_tile(gA, gB, sA, sB, wv, 0, 0);
    stage_tile(gA, gB, sA, sB, wv, 1, 1);

    const int po = (quad ^ (fm & 3)) * 8;

    for (int t = 0; t < 32; ++t) {
        const int bf = t % 3;
        if (t + 2 < 32)
            stage_tile(gA, gB, sA, sB, wv, t + 2, (t + 2) % 3);

        // counted wait: stage(t) retired; deeper prefetches stay in flight.
        if (t < 30)       asm volatile("s_waitcnt vmcnt(8)" ::: "memory");
        else if (t == 30) asm volatile("s_waitcnt vmcnt(4)" ::: "memory");
        else              asm volatile("s_waitcnt vmcnt(0)" ::: "memory");
        __builtin_amdgcn_sched_barrier(0);
        __builtin_amdgcn_s_barrier();            // tile t visible to all waves
        __builtin_amdgcn_sched_barrier(0);

        half8 b[4];
        #pragma unroll
        for (int j = 0; j < 4; ++j)
            b[j] = *(const half8*)&sB[bf][(wn + j * 16 + fm) * 32 + po];

        __builtin_amdgcn_s_setprio(1);
        #pragma unroll
        for (int i = 0; i < 8; ++i) {
            half8 ai = *(const half8*)&sA[bf][(wm + i * 16 + fm) * 32 + po];
            #pragma unroll
            for (int j = 0; j < 4; ++j)
                acc[i][j] = __builtin_amdgcn_mfma_f32_16x16x32_f16(ai, b[j], acc[i][j], 0, 0, 0);
        }
        __builtin_amdgcn_s_setprio(0);

        // all LDS reads of buf bf retired before any wave re-stages into it
        asm volatile("s_waitcnt lgkmcnt(0)" ::: "memory");
        __builtin_amdgcn_sched_barrier(0);
        __builtin_amdgcn_s_barrier();
        __builtin_amdgcn_sched_barrier(0);
    }

    // Epilogue scatter (same addressing as round-10 gemm_body, 8-wave tile).
    const int rr = quad * 4;
    if (mode == 0) {
        const int nmask = (1 << nsh) - 1;
        #pragma unroll
        for (int i = 0; i < 8; ++i)
            #pragma unroll
            for (int r = 0; r < 4; ++r) {
                const int m = m0 + wm + i * 16 + rr + r;
                const int b = m >> nsh, n = m & nmask;
                #pragma unroll
                for (int j = 0; j < 4; ++j) {
                    const int c = n0 + wn + j * 16 + fm;
                    Yh[((((size_t)b * H_ + (c >> 6)) << nsh) + n) * 64 + (c & 63)] = (_Float16)acc[i][j][r];
                }
            }
    } else {
        const int nmask = (1 << nsh) - 1;
        #pragma unroll
        for (int i = 0; i < 8; ++i)
            #pragma unroll
            for (int r = 0; r < 4; ++r) {
                const int m = m0 + wm + i * 16 + rr + r;
                const int b = m >> nsh, n = m & nmask;
                #pragma unroll
                for (int j = 0; j < 4; ++j) {
                    const int c = n0 + wn + j * 16 + fm;
                    Yh[(((size_t)(b * H_ + (c >> 6)) * 64) + (c & 63)) * NK + n] = (_Float16)acc[i][j][r];
                }
            }
    }
}

// ---------------------------------------------------------------------------
// Old 128x128 GEMM body, kept for the (small) output projection.
// ---------------------------------------------------------------------------
__device__ __forceinline__ void gemm_body(const _Float16* __restrict__ A,
                                          const _Float16* __restrict__ Bw,
                                          float* __restrict__ Yf,
                                          const float* __restrict__ bias,
                                          _Float16* sA, _Float16* sB)
{
    const int tid = threadIdx.x;
    const int lane = tid & 63, wave = tid >> 6;
    const int n0 = blockIdx.x * 128, m0 = blockIdx.y * 128;
    const int wm = (wave >> 1) * 64, wn = (wave & 1) * 64;
    const int fm = lane & 15, quad = lane >> 4;

    const int srow = wave * 32 + (lane >> 3);
    const int soct = (lane & 7) ^ (srow & 7);
    const _Float16* gA = A  + (size_t)(m0 + srow) * KK + soct * 8;
    const _Float16* gB = Bw + (size_t)(n0 + srow) * KK + soct * 8;

    float4v acc[4][4];
    #pragma unroll
    for (int i = 0; i < 4; ++i)
        #pragma unroll
        for (int j = 0; j < 4; ++j)
            #pragma unroll
            for (int e = 0; e < 4; ++e) acc[i][j][e] = 0.0f;

    for (int k0 = 0; k0 < KK; k0 += 64) {
        __syncthreads();
        #pragma unroll
        for (int u = 0; u < 4; ++u) {
            g2l16(gA + (size_t)u * 8 * KK + k0, &sA[(wave * 32 + u * 8) * 64]);
            g2l16(gB + (size_t)u * 8 * KK + k0, &sB[(wave * 32 + u * 8) * 64]);
        }
        __syncthreads();

        #pragma unroll
        for (int ks = 0; ks < 2; ++ks) {
            const int po = ((ks * 4 + quad) ^ (fm & 7)) * 8;
            half8 a[4], b[4];
            #pragma unroll
            for (int i = 0; i < 4; ++i) {
                a[i] = *(const half8*)&sA[(wm + i * 16 + fm) * 64 + po];
                b[i] = *(const half8*)&sB[(wn + i * 16 + fm) * 64 + po];
            }
            #pragma unroll
            for (int i = 0; i < 4; ++i)
                #pragma unroll
                for (int j = 0; j < 4; ++j)
                    acc[i][j] = __builtin_amdgcn_mfma_f32_16x16x32_f16(a[i], b[j], acc[i][j], 0, 0, 0);
        }
    }

    const int rr = quad * 4;
    #pragma unroll
    for (int i = 0; i < 4; ++i)
        #pragma unroll
        for (int r = 0; r < 4; ++r) {
            const int m = m0 + wm + i * 16 + rr + r;
            #pragma unroll
            for (int j = 0; j < 4; ++j) {
                const int c = n0 + wn + j * 16 + fm;
                Yf[(size_t)m * 1024 + c] = acc[i][j][r] + bias[c];
            }
        }
}

// Output projection (fp32 + bias).
__global__ __launch_bounds__(256) void gemm_out(const _Float16* __restrict__ A,
                                                const _Float16* __restrict__ Bw,
                                                float* __restrict__ Yf,
                                                const float* __restrict__ bias)
{
    __shared__ _Float16 sA[128 * 64];
    __shared__ _Float16 sB[128 * 64];
    gemm_body(A, Bw, Yf, bias, sA, sB);
}

// ---------------------------------------------------------------------------
// RoPE on q AND k in one launch (flat index).  q gets scale 0.125 (D^-0.5).
// f = 10000^(-i/32) via 5 predicated exact double multiplies (i bit decomp).
// ---------------------------------------------------------------------------
__global__ __launch_bounds__(256) void rope_qk(_Float16* __restrict__ qh,
                                               _Float16* __restrict__ kh,
                                               const int* __restrict__ qpos,
                                               const int* __restrict__ kpos)
{
    int idx = blockIdx.x * 256 + threadIdx.x;
    const int QTOT = B_ * H_ * NQ * 32;
    _Float16* t; const int* pos; int Nseq; float scale;
    if (idx < QTOT) { t = qh; pos = qpos; Nseq = NQ; scale = 0.125f; }
    else { idx -= QTOT; t = kh; pos = kpos; Nseq = NK; scale = 1.0f; }

    const int i = idx & 31;
    const int n = (idx >> 5) % Nseq;
    const int b = (idx / (32 * Nseq)) >> 4;

    // f = 10000^(-i/32) = prod over set bits of i of 10^(-bit/8)
    double f = 1.0;
    if (i & 1)  f *= 0.7498942093324559;    // 10^-0.125
    if (i & 2)  f *= 0.5623413251903491;    // 10^-0.25
    if (i & 4)  f *= 0.31622776601683794;   // 10^-0.5
    if (i & 8)  f *= 0.1;
    if (i & 16) f *= 0.01;

    const double ang = (double)pos[b * Nseq + n] * f;
    const double TWO_PI = 6.2831853071795864769;
    const double INV_TWO_PI = 0.15915494309189533577;
    const float red = (float)(ang - TWO_PI * floor(ang * INV_TWO_PI));
    float s, c;
    sincosf(red, &s, &c);

    const size_t base = ((size_t)(idx >> 5)) * 64 + i;
    const float x1 = (float)t[base];
    const float x2 = (float)t[base + 32];
    t[base]      = (_Float16)((x1 * c - x2 * s) * scale);
    t[base + 32] = (_Float16)((x2 * c + x1 * s) * scale);
}

// ---------------------------------------------------------------------------
// Fused flash attention (round 10, unchanged): LDS-shared K/V tiles,
// double-buffered global_load_lds staging, 8 waves each owning 16 queries.
// ---------------------------------------------------------------------------
__global__ __launch_bounds__(512) void attn_fused(const _Float16* __restrict__ qh,
                                                  const _Float16* __restrict__ kh,
                                                  const _Float16* __restrict__ vt,
                                                  _Float16* __restrict__ xw16)
{
    __shared__ _Float16 sK[2][64 * 64];
    __shared__ _Float16 sV[2][64 * 64];
    __shared__ _Float16 ps[8][16][66];

    const int tid = threadIdx.x;
    const int lane = tid & 63, wv = tid >> 6;   // 8 waves
    const int bhi = blockIdx.x & 63;            // XCD key
    const int qquad = blockIdx.x >> 6;          // 0..3
    const size_t bh = (size_t)bhi;
    const int qt = qquad * 8 + wv;              // q-tile 0..31 (16 queries)

    const int fm = lane & 15;
    const int quad = lane >> 4;
    const int fq = quad * 8;

    const _Float16* kb = kh + bh * NK * 64;
    const _Float16* vb = vt + bh * (size_t)64 * NK;

    const int r0 = lane >> 3;
    const int c4 = lane & 7;
    const int sch = c4 ^ r0;
    const _Float16* gK = kb + (size_t)(wv * 8 + r0) * 64 + sch * 8;
    const _Float16* gV = vb + (size_t)(wv * 8 + r0) * NK + sch * 8;

    const _Float16* qb = qh + (bh * NQ + (size_t)qt * 16) * 64;
    half8 aq[2];
    aq[0] = *(const half8*)(qb + (size_t)fm * 64 + fq);
    aq[1] = *(const half8*)(qb + (size_t)fm * 64 + 32 + fq);

    float l_acc[4] = {};
    float4v O[4];
    #pragma unroll
    for (int j = 0; j < 4; ++j)
        #pragma unroll
        for (int e = 0; e < 4; ++e) O[j][e] = 0.0f;

    const float4v z4 = {0.0f, 0.0f, 0.0f, 0.0f};

    g2l16(gK, &sK[0][wv * 512]);
    g2l16(gV, &sV[0][wv * 512]);
    __syncthreads();

    for (int it = 0; it < 32; ++it) {
        const int cur = it & 1;
        if (it < 31) {
            g2l16(gK + (size_t)(it + 1) * 64 * 64, &sK[cur ^ 1][wv * 512]);
            g2l16(gV + (it + 1) * 64,              &sV[cur ^ 1][wv * 512]);
        }
        const _Float16* Kc = sK[cur];
        const _Float16* Vc = sV[cur];

        half8 bk[4][2];
        #pragma unroll
        for (int j = 0; j < 4; ++j)
            #pragma unroll
            for (int ks = 0; ks < 2; ++ks)
                bk[j][ks] = *(const half8*)&Kc[(j * 16 + fm) * 64 + (((ks * 4 + quad) ^ (fm & 7)) * 8)];

        float4v s[4];
        __builtin_amdgcn_s_setprio(1);
        #pragma unroll
        for (int j = 0; j < 4; ++j) {
            s[j] = __builtin_amdgcn_mfma_f32_16x16x32_f16(aq[0], bk[j][0], z4, 0, 0, 0);
            s[j] = __builtin_amdgcn_mfma_f32_16x16x32_f16(aq[1], bk[j][1], s[j], 0, 0, 0);
        }
        __builtin_amdgcn_s_setprio(0);

        half8 bv[4][2];
        #pragma unroll
        for (int j = 0; j < 4; ++j)
            #pragma unroll
            for (int ks = 0; ks < 2; ++ks)
                bv[j][ks] = *(const half8*)&Vc[(j * 16 + fm) * 64 + (((ks * 4 + quad) ^ (fm & 7)) * 8)];

        #pragma unroll
        for (int j = 0; j < 4; ++j)
            #pragma unroll
            for (int r = 0; r < 4; ++r) {
                const float p = __expf(s[j][r]);
                l_acc[r] += p;
                ps[wv][quad * 4 + r][16 * j + fm] = (_Float16)p;
            }

        __builtin_amdgcn_s_setprio(1);
        #pragma unroll
        for (int ks = 0; ks < 2; ++ks) {
            half8 pa = *(const half8*)&ps[wv][fm][ks * 32 + fq];
            #pragma unroll
            for (int j = 0; j < 4; ++j)
                O[j] = __builtin_amdgcn_mfma_f32_16x16x32_f16(pa, bv[j][ks], O[j], 0, 0, 0);
        }
        __builtin_amdgcn_s_setprio(0);

        __syncthreads();
    }

    #pragma unroll
    for (int r = 0; r < 4; ++r) {
        float l = l_acc[r];
        l += __shfl_xor(l, 1);
        l += __shfl_xor(l, 2);
        l += __shfl_xor(l, 4);
        l += __shfl_xor(l, 8);
        const float inv = 1.0f / l;
        const int qr = quad * 4 + r;
        const int row = (bhi >> 4) * 512 + qt * 16 + qr;
        #pragma unroll
        for (int j = 0; j < 4; ++j) {
            const int col = (bhi & 15) * 64 + j * 16 + fm;
            xw16[(size_t)row * 1024 + col] = (_Float16)(O[j][r] * inv);
        }
    }
}

// ---------------------------------------------------------------------------
extern "C" void kernel_launch(void* const* d_in, const int* in_sizes, int n_in,
                              void* d_out, int out_size, void* d_ws, size_t ws_size,
                              hipStream_t stream)
{
    const float* query = (const float*)d_in[0];
    const float* key   = (const float*)d_in[1];
    const float* value = (const float*)d_in[2];
    const int*   qpos  = (const int*)d_in[3];
    const int*   kpos  = (const int*)d_in[4];
    const float* Wq    = (const float*)d_in[5];
    const float* Wk    = (const float*)d_in[6];
    const float* Wv    = (const float*)d_in[7];
    const float* Wp    = (const float*)d_in[8];
    const float* bp    = (const float*)d_in[9];
    float* out = (float*)d_out;

    // ws layout (MiB), 80 total:
    //  0..16 : xk16 [8192][1024] fp16 (free after gemm_qkv256)
    // 16..32 : xv16 [8192][1024] fp16 (free after gemm_qkv256)
    // 32..36 : xq16 / xw16 [2048][1024] fp16
    // 36..44 : W16 x4 slots (Wq,Wk,Wv,Wp)
    // 44..48 : qh  [B,H,512,64] fp16
    // 48..64 : kh  [B,H,2048,64] fp16
    // 64..80 : vt  [B,H,64,2048] fp16
    char* ws = (char*)d_ws;
    _Float16* xk16  = (_Float16*)(ws);
    _Float16* xv16  = (_Float16*)(ws + (16u << 20));
    _Float16* xq16  = (_Float16*)(ws + (32u << 20));
    _Float16* W16   = (_Float16*)(ws + (36u << 20));
    _Float16* qhp   = (_Float16*)(ws + (44u << 20));
    _Float16* khp   = (_Float16*)(ws + (48u << 20));
    _Float16* vtp   = (_Float16*)(ws + (64u << 20));

    cvt_w4 <<<4096, 256, 0, stream>>>(Wq, Wk, Wv, Wp, W16);
    cvt_qkv<<<18432, 256, 0, stream>>>(query, key, value, xq16, xk16, xv16);

    gemm_qkv256<<<288, 512, 0, stream>>>(xq16, xk16, xv16, W16, qhp, khp, vtp);

    rope_qk<<<(B_ * H_ * (NQ + NK) * 32) / 256, 256, 0, stream>>>(qhp, khp, qpos, kpos);

    attn_fused<<<256, 512, 0, stream>>>(qhp, khp, vtp, xq16);

    gemm_out<<<dim3(8, 16), 256, 0, stream>>>(xq16, W16 + (3u << 20), out, bp);
}

// Round 4
// 268.306 us; speedup vs baseline: 1.0949x; 1.0949x over previous
//
#include <hip/hip_runtime.h>
#include <math.h>

// Round 12: revert projection GEMM to the proven 128^2/BK=64/4-wave structure
// (round-10: 0 bank conflicts, ~5 blocks/CU) but KEEP round-11's only win:
// the XCD-grouped linear block decode (FETCH 150MB -> 43MB, verified).
//  - grid 1152 linear; (xcd = lbid&7, t = lbid>>6 ... bijective decode) puts
//    all 8 n-blocks of one A-panel consecutively on ONE XCD's L2.
//  - round-11 failure analysed: 96KB LDS -> 1 block/CU + 288-block grid tail
//    (2x serial) + BK=32 swizzle bank conflicts (3.5M). All three reverted.
//  - cvt_w4 + cvt_qkv merged into one cvt_all launch.
// rope (predicated f64 mults), attn_fused, gemm_out unchanged.
#define B_ 4
#define NQ 512
#define NK 2048
#define C_ 1024
#define H_ 16
#define D_ 64
#define KK 1024

typedef __attribute__((ext_vector_type(8))) _Float16 half8;
typedef __attribute__((ext_vector_type(4))) _Float16 half4;
typedef __attribute__((ext_vector_type(4))) float float4v;

// async global->LDS, 16B per lane (wave-uniform LDS base + lane*16 by HW)
__device__ __forceinline__ void g2l16(const _Float16* g, _Float16* l)
{
    __builtin_amdgcn_global_load_lds(
        (const __attribute__((address_space(1))) unsigned int*)g,
        (__attribute__((address_space(3))) unsigned int*)l, 16, 0, 0);
}

// ---------------------------------------------------------------------------
// Merged converts: blk<4096 -> W slots; else q/k/v rows.
// ---------------------------------------------------------------------------
__global__ __launch_bounds__(256) void cvt_all(const float* __restrict__ W0,
                                               const float* __restrict__ W1,
                                               const float* __restrict__ W2,
                                               const float* __restrict__ W3,
                                               const float* __restrict__ q,
                                               const float* __restrict__ k,
                                               const float* __restrict__ v,
                                               _Float16* __restrict__ W16,
                                               _Float16* __restrict__ xq,
                                               _Float16* __restrict__ xk,
                                               _Float16* __restrict__ xv)
{
    const int blk = blockIdx.x;
    const float* src; _Float16* dst; int row;
    if (blk < 4096) {
        const int w = blk >> 10; row = blk & 1023;
        src = (w == 0) ? W0 : (w == 1) ? W1 : (w == 2) ? W2 : W3;
        dst = W16 + ((size_t)w << 20);
    } else {
        const int b2 = blk - 4096;
        if (b2 < 2048)       { src = q; dst = xq; row = b2; }
        else if (b2 < 10240) { src = k; dst = xk; row = b2 - 2048; }
        else                 { src = v; dst = xv; row = b2 - 10240; }
    }
    const int col = threadIdx.x * 4;
    float4 f = *(const float4*)(src + (size_t)row * 1024 + col);
    half4 h;
    h[0] = (_Float16)f.x; h[1] = (_Float16)f.y;
    h[2] = (_Float16)f.z; h[3] = (_Float16)f.w;
    *(half4*)(dst + (size_t)row * 1024 + col) = h;
}

// ---------------------------------------------------------------------------
// 128x128 tile, BK=64, 4 waves, 4x4 16x16x32 MFMA; global_load_lds staging
// with XOR-octet swizzle (measured conflict-free).  m0/n0 passed in.
// mode 0: fp16 scatter [B,H,1<<nsh,64]; mode 1: fp32+bias row-major;
// mode 2: fp16 scatter transposed [B,H,64,NK].
// ---------------------------------------------------------------------------
__device__ __forceinline__ void gemm_body(const _Float16* __restrict__ A,
                                          const _Float16* __restrict__ Bw,
                                          _Float16* __restrict__ Yh,
                                          float* __restrict__ Yf,
                                          int mode, int nsh, int m0, int n0,
                                          const float* __restrict__ bias,
                                          _Float16* sA, _Float16* sB)
{
    const int tid = threadIdx.x;
    const int lane = tid & 63, wave = tid >> 6;
    const int wm = (wave >> 1) * 64, wn = (wave & 1) * 64;
    const int fm = lane & 15, quad = lane >> 4;

    const int srow = wave * 32 + (lane >> 3);
    const int soct = (lane & 7) ^ (srow & 7);
    const _Float16* gA = A  + (size_t)(m0 + srow) * KK + soct * 8;
    const _Float16* gB = Bw + (size_t)(n0 + srow) * KK + soct * 8;

    float4v acc[4][4];
    #pragma unroll
    for (int i = 0; i < 4; ++i)
        #pragma unroll
        for (int j = 0; j < 4; ++j)
            #pragma unroll
            for (int e = 0; e < 4; ++e) acc[i][j][e] = 0.0f;

    for (int k0 = 0; k0 < KK; k0 += 64) {
        __syncthreads();
        #pragma unroll
        for (int u = 0; u < 4; ++u) {
            g2l16(gA + (size_t)u * 8 * KK + k0, &sA[(wave * 32 + u * 8) * 64]);
            g2l16(gB + (size_t)u * 8 * KK + k0, &sB[(wave * 32 + u * 8) * 64]);
        }
        __syncthreads();

        #pragma unroll
        for (int ks = 0; ks < 2; ++ks) {
            const int po = ((ks * 4 + quad) ^ (fm & 7)) * 8;
            half8 a[4], b[4];
            #pragma unroll
            for (int i = 0; i < 4; ++i) {
                a[i] = *(const half8*)&sA[(wm + i * 16 + fm) * 64 + po];
                b[i] = *(const half8*)&sB[(wn + i * 16 + fm) * 64 + po];
            }
            __builtin_amdgcn_s_setprio(1);
            #pragma unroll
            for (int i = 0; i < 4; ++i)
                #pragma unroll
                for (int j = 0; j < 4; ++j)
                    acc[i][j] = __builtin_amdgcn_mfma_f32_16x16x32_f16(a[i], b[j], acc[i][j], 0, 0, 0);
            __builtin_amdgcn_s_setprio(0);
        }
    }

    const int rr = quad * 4;
    if (mode == 0) {
        const int nmask = (1 << nsh) - 1;
        #pragma unroll
        for (int i = 0; i < 4; ++i)
            #pragma unroll
            for (int r = 0; r < 4; ++r) {
                const int m = m0 + wm + i * 16 + rr + r;
                const int b = m >> nsh, n = m & nmask;
                #pragma unroll
                for (int j = 0; j < 4; ++j) {
                    const int c = n0 + wn + j * 16 + fm;
                    Yh[((((size_t)b * H_ + (c >> 6)) << nsh) + n) * 64 + (c & 63)] = (_Float16)acc[i][j][r];
                }
            }
    } else if (mode == 2) {
        const int nmask = (1 << nsh) - 1;
        #pragma unroll
        for (int i = 0; i < 4; ++i)
            #pragma unroll
            for (int r = 0; r < 4; ++r) {
                const int m = m0 + wm + i * 16 + rr + r;
                const int b = m >> nsh, n = m & nmask;
                #pragma unroll
                for (int j = 0; j < 4; ++j) {
                    const int c = n0 + wn + j * 16 + fm;
                    Yh[(((size_t)(b * H_ + (c >> 6)) * 64) + (c & 63)) * NK + n] = (_Float16)acc[i][j][r];
                }
            }
    } else {
        #pragma unroll
        for (int i = 0; i < 4; ++i)
            #pragma unroll
            for (int r = 0; r < 4; ++r) {
                const int m = m0 + wm + i * 16 + rr + r;
                #pragma unroll
                for (int j = 0; j < 4; ++j) {
                    const int c = n0 + wn + j * 16 + fm;
                    Yf[(size_t)m * 1024 + c] = acc[i][j][r] + bias[c];
                }
            }
    }
}

// Q/K/V projections, XCD-grouped linear grid of 1152 blocks.
// panel y = xcd + 8*t (bijective over 0..143), n-block = seq&7.
// y<64: K panel; y<128: V panel; else Q panel.
__global__ __launch_bounds__(256) void gemm_qkv(const _Float16* __restrict__ xq,
                                                const _Float16* __restrict__ xk,
                                                const _Float16* __restrict__ xv,
                                                const _Float16* __restrict__ W16,
                                                _Float16* __restrict__ qhp,
                                                _Float16* __restrict__ khp,
                                                _Float16* __restrict__ vtp)
{
    __shared__ _Float16 sA[128 * 64];
    __shared__ _Float16 sB[128 * 64];

    const int lbid = blockIdx.x;            // 0..1151
    const int xcd = lbid & 7;
    const int seq = lbid >> 3;              // 0..143
    const int y = xcd + 8 * (seq >> 3);     // m-panel 0..143
    const int n0 = (seq & 7) * 128;

    if (y < 64)
        gemm_body(xk, W16 + (1u << 20), khp, nullptr, 0, 11, y * 128, n0, nullptr, sA, sB);
    else if (y < 128)
        gemm_body(xv, W16 + (2u << 20), vtp, nullptr, 2, 11, (y - 64) * 128, n0, nullptr, sA, sB);
    else
        gemm_body(xq, W16, qhp, nullptr, 0, 9, (y - 128) * 128, n0, nullptr, sA, sB);
}

// Output projection (fp32 + bias).
__global__ __launch_bounds__(256) void gemm_out(const _Float16* __restrict__ A,
                                                const _Float16* __restrict__ Bw,
                                                float* __restrict__ Yf,
                                                const float* __restrict__ bias)
{
    __shared__ _Float16 sA[128 * 64];
    __shared__ _Float16 sB[128 * 64];
    gemm_body(A, Bw, nullptr, Yf, 1, 0, blockIdx.y * 128, blockIdx.x * 128, bias, sA, sB);
}

// ---------------------------------------------------------------------------
// RoPE on q AND k in one launch (flat index).  q gets scale 0.125 (D^-0.5).
// f = 10000^(-i/32) via 5 predicated exact double multiplies (i bit decomp).
// ---------------------------------------------------------------------------
__global__ __launch_bounds__(256) void rope_qk(_Float16* __restrict__ qh,
                                               _Float16* __restrict__ kh,
                                               const int* __restrict__ qpos,
                                               const int* __restrict__ kpos)
{
    int idx = blockIdx.x * 256 + threadIdx.x;
    const int QTOT = B_ * H_ * NQ * 32;
    _Float16* t; const int* pos; int Nseq; float scale;
    if (idx < QTOT) { t = qh; pos = qpos; Nseq = NQ; scale = 0.125f; }
    else { idx -= QTOT; t = kh; pos = kpos; Nseq = NK; scale = 1.0f; }

    const int i = idx & 31;
    const int n = (idx >> 5) % Nseq;
    const int b = (idx / (32 * Nseq)) >> 4;

    // f = 10000^(-i/32) = prod over set bits of i of 10^(-bit/8)
    double f = 1.0;
    if (i & 1)  f *= 0.7498942093324559;    // 10^-0.125
    if (i & 2)  f *= 0.5623413251903491;    // 10^-0.25
    if (i & 4)  f *= 0.31622776601683794;   // 10^-0.5
    if (i & 8)  f *= 0.1;
    if (i & 16) f *= 0.01;

    const double ang = (double)pos[b * Nseq + n] * f;
    const double TWO_PI = 6.2831853071795864769;
    const double INV_TWO_PI = 0.15915494309189533577;
    const float red = (float)(ang - TWO_PI * floor(ang * INV_TWO_PI));
    float s, c;
    sincosf(red, &s, &c);

    const size_t base = ((size_t)(idx >> 5)) * 64 + i;
    const float x1 = (float)t[base];
    const float x2 = (float)t[base + 32];
    t[base]      = (_Float16)((x1 * c - x2 * s) * scale);
    t[base + 32] = (_Float16)((x2 * c + x1 * s) * scale);
}

// ---------------------------------------------------------------------------
// Fused flash attention (round 10, unchanged): LDS-shared K/V tiles,
// double-buffered global_load_lds staging, 8 waves each owning 16 queries.
// ---------------------------------------------------------------------------
__global__ __launch_bounds__(512) void attn_fused(const _Float16* __restrict__ qh,
                                                  const _Float16* __restrict__ kh,
                                                  const _Float16* __restrict__ vt,
                                                  _Float16* __restrict__ xw16)
{
    __shared__ _Float16 sK[2][64 * 64];
    __shared__ _Float16 sV[2][64 * 64];
    __shared__ _Float16 ps[8][16][66];

    const int tid = threadIdx.x;
    const int lane = tid & 63, wv = tid >> 6;   // 8 waves
    const int bhi = blockIdx.x & 63;            // XCD key
    const int qquad = blockIdx.x >> 6;          // 0..3
    const size_t bh = (size_t)bhi;
    const int qt = qquad * 8 + wv;              // q-tile 0..31 (16 queries)

    const int fm = lane & 15;
    const int quad = lane >> 4;
    const int fq = quad * 8;

    const _Float16* kb = kh + bh * NK * 64;
    const _Float16* vb = vt + bh * (size_t)64 * NK;

    const int r0 = lane >> 3;
    const int c4 = lane & 7;
    const int sch = c4 ^ r0;
    const _Float16* gK = kb + (size_t)(wv * 8 + r0) * 64 + sch * 8;
    const _Float16* gV = vb + (size_t)(wv * 8 + r0) * NK + sch * 8;

    const _Float16* qb = qh + (bh * NQ + (size_t)qt * 16) * 64;
    half8 aq[2];
    aq[0] = *(const half8*)(qb + (size_t)fm * 64 + fq);
    aq[1] = *(const half8*)(qb + (size_t)fm * 64 + 32 + fq);

    float l_acc[4] = {};
    float4v O[4];
    #pragma unroll
    for (int j = 0; j < 4; ++j)
        #pragma unroll
        for (int e = 0; e < 4; ++e) O[j][e] = 0.0f;

    const float4v z4 = {0.0f, 0.0f, 0.0f, 0.0f};

    g2l16(gK, &sK[0][wv * 512]);
    g2l16(gV, &sV[0][wv * 512]);
    __syncthreads();

    for (int it = 0; it < 32; ++it) {
        const int cur = it & 1;
        if (it < 31) {
            g2l16(gK + (size_t)(it + 1) * 64 * 64, &sK[cur ^ 1][wv * 512]);
            g2l16(gV + (it + 1) * 64,              &sV[cur ^ 1][wv * 512]);
        }
        const _Float16* Kc = sK[cur];
        const _Float16* Vc = sV[cur];

        half8 bk[4][2];
        #pragma unroll
        for (int j = 0; j < 4; ++j)
            #pragma unroll
            for (int ks = 0; ks < 2; ++ks)
                bk[j][ks] = *(const half8*)&Kc[(j * 16 + fm) * 64 + (((ks * 4 + quad) ^ (fm & 7)) * 8)];

        float4v s[4];
        __builtin_amdgcn_s_setprio(1);
        #pragma unroll
        for (int j = 0; j < 4; ++j) {
            s[j] = __builtin_amdgcn_mfma_f32_16x16x32_f16(aq[0], bk[j][0], z4, 0, 0, 0);
            s[j] = __builtin_amdgcn_mfma_f32_16x16x32_f16(aq[1], bk[j][1], s[j], 0, 0, 0);
        }
        __builtin_amdgcn_s_setprio(0);

        half8 bv[4][2];
        #pragma unroll
        for (int j = 0; j < 4; ++j)
            #pragma unroll
            for (int ks = 0; ks < 2; ++ks)
                bv[j][ks] = *(const half8*)&Vc[(j * 16 + fm) * 64 + (((ks * 4 + quad) ^ (fm & 7)) * 8)];

        #pragma unroll
        for (int j = 0; j < 4; ++j)
            #pragma unroll
            for (int r = 0; r < 4; ++r) {
                const float p = __expf(s[j][r]);
                l_acc[r] += p;
                ps[wv][quad * 4 + r][16 * j + fm] = (_Float16)p;
            }

        __builtin_amdgcn_s_setprio(1);
        #pragma unroll
        for (int ks = 0; ks < 2; ++ks) {
            half8 pa = *(const half8*)&ps[wv][fm][ks * 32 + fq];
            #pragma unroll
            for (int j = 0; j < 4; ++j)
                O[j] = __builtin_amdgcn_mfma_f32_16x16x32_f16(pa, bv[j][ks], O[j], 0, 0, 0);
        }
        __builtin_amdgcn_s_setprio(0);

        __syncthreads();
    }

    #pragma unroll
    for (int r = 0; r < 4; ++r) {
        float l = l_acc[r];
        l += __shfl_xor(l, 1);
        l += __shfl_xor(l, 2);
        l += __shfl_xor(l, 4);
        l += __shfl_xor(l, 8);
        const float inv = 1.0f / l;
        const int qr = quad * 4 + r;
        const int row = (bhi >> 4) * 512 + qt * 16 + qr;
        #pragma unroll
        for (int j = 0; j < 4; ++j) {
            const int col = (bhi & 15) * 64 + j * 16 + fm;
            xw16[(size_t)row * 1024 + col] = (_Float16)(O[j][r] * inv);
        }
    }
}

// ---------------------------------------------------------------------------
extern "C" void kernel_launch(void* const* d_in, const int* in_sizes, int n_in,
                              void* d_out, int out_size, void* d_ws, size_t ws_size,
                              hipStream_t stream)
{
    const float* query = (const float*)d_in[0];
    const float* key   = (const float*)d_in[1];
    const float* value = (const float*)d_in[2];
    const int*   qpos  = (const int*)d_in[3];
    const int*   kpos  = (const int*)d_in[4];
    const float* Wq    = (const float*)d_in[5];
    const float* Wk    = (const float*)d_in[6];
    const float* Wv    = (const float*)d_in[7];
    const float* Wp    = (const float*)d_in[8];
    const float* bp    = (const float*)d_in[9];
    float* out = (float*)d_out;

    // ws layout (MiB), 80 total:
    //  0..16 : xk16 [8192][1024] fp16 (free after gemm_qkv)
    // 16..32 : xv16 [8192][1024] fp16 (free after gemm_qkv)
    // 32..36 : xq16 / xw16 [2048][1024] fp16
    // 36..44 : W16 x4 slots (Wq,Wk,Wv,Wp)
    // 44..48 : qh  [B,H,512,64] fp16
    // 48..64 : kh  [B,H,2048,64] fp16
    // 64..80 : vt  [B,H,64,2048] fp16
    char* ws = (char*)d_ws;
    _Float16* xk16  = (_Float16*)(ws);
    _Float16* xv16  = (_Float16*)(ws + (16u << 20));
    _Float16* xq16  = (_Float16*)(ws + (32u << 20));
    _Float16* W16   = (_Float16*)(ws + (36u << 20));
    _Float16* qhp   = (_Float16*)(ws + (44u << 20));
    _Float16* khp   = (_Float16*)(ws + (48u << 20));
    _Float16* vtp   = (_Float16*)(ws + (64u << 20));

    cvt_all<<<22528, 256, 0, stream>>>(Wq, Wk, Wv, Wp, query, key, value,
                                       W16, xq16, xk16, xv16);

    gemm_qkv<<<1152, 256, 0, stream>>>(xq16, xk16, xv16, W16, qhp, khp, vtp);

    rope_qk<<<(B_ * H_ * (NQ + NK) * 32) / 256, 256, 0, stream>>>(qhp, khp, qpos, kpos);

    attn_fused<<<256, 512, 0, stream>>>(qhp, khp, vtp, xq16);

    gemm_out<<<dim3(8, 16), 256, 0, stream>>>(xq16, W16 + (3u << 20), out, bp);
}